// Round 1
// 943.652 us; speedup vs baseline: 1.2028x; 1.2028x over previous
//
#include <hip/hip_runtime.h>

// Decoder: B=64, T=32, R=49, E=512, L=2, V=30000. fp32 in/out, bf16 MFMA inside.
#define B_ 64
#define T_ 32
#define R_ 49
#define E_ 512
#define V_ 30000

using bfrag = __attribute__((ext_vector_type(8))) short;   // 8 bf16 (4 VGPRs)
using ffrag = __attribute__((ext_vector_type(4))) float;   // 4 fp32 acc

__device__ __forceinline__ float bf2f(short u) {
    union { unsigned u32; float f; } x;
    x.u32 = ((unsigned)(unsigned short)u) << 16;
    return x.f;
}
__device__ __forceinline__ unsigned short f2bf(float f) {
    union { float f; unsigned u; } x; x.f = f;
    unsigned r = x.u + 0x7fffu + ((x.u >> 16) & 1u);   // RNE
    return (unsigned short)(r >> 16);
}
__device__ __forceinline__ float sigm(float x) { return 1.f / (1.f + __expf(-x)); }

#define GLDS(g, l) __builtin_amdgcn_global_load_lds( \
    (const __attribute__((address_space(1))) void*)(g), \
    (__attribute__((address_space(3))) void*)(l), 16, 0, 0)

// ---------------------------------------------------------------------------
// fp32 -> bf16 bulk convert. n8 = elem_count/8.
// ---------------------------------------------------------------------------
__global__ __launch_bounds__(256)
void cvt_kernel(const float* __restrict__ src, unsigned short* __restrict__ dst, int n8)
{
    int i = blockIdx.x * 256 + threadIdx.x;
    if (i >= n8) return;
    const float4* s = (const float4*)src + (size_t)i * 2;
    float4 a = s[0], b = s[1];
    bfrag o;
    o[0] = (short)f2bf(a.x); o[1] = (short)f2bf(a.y);
    o[2] = (short)f2bf(a.z); o[3] = (short)f2bf(a.w);
    o[4] = (short)f2bf(b.x); o[5] = (short)f2bf(b.y);
    o[6] = (short)f2bf(b.z); o[7] = (short)f2bf(b.w);
    *(bfrag*)(dst + (size_t)i * 8) = o;
}

// ---------------------------------------------------------------------------
// C = A @ W^T (+bias1+bias2), fp32 out. A:[M,K] bf16, W:[N,K] bf16, bias fp32.
// m97 structure: 128x128 tile, BK=32, global_load_lds w=16, mfma 16x16x32 bf16.
// XCD-aware bijective block swizzle (T1): consecutive same-XCD blocks share
// the same W-tile (n0), so per-XCD L2 stops refetching it.
// ---------------------------------------------------------------------------
__global__ __launch_bounds__(256)
void gemm_bt(const unsigned short* __restrict__ A,
             const unsigned short* __restrict__ W,
             const float* __restrict__ bias1,
             const float* __restrict__ bias2,
             float* __restrict__ outp,
             int M, int N, int K)
{
    __shared__ __align__(16) unsigned short As[128 * 32];
    __shared__ __align__(16) unsigned short Bs[128 * 32];
    const int tid  = threadIdx.x;
    const int wave = tid >> 6, lane = tid & 63;
    const int lrow = lane & 15, kq = lane >> 4;

    // --- XCD swizzle (nwg divisible by 8 for both launch shapes) ---
    const int gx = gridDim.x;
    const int nwg = gx * gridDim.y;
    int bid = blockIdx.y * gx + blockIdx.x;
    if ((nwg & 7) == 0) {
        const int cpx = nwg >> 3;
        bid = (bid & 7) * cpx + (bid >> 3);
    }
    const int m0 = (bid % gx) * 128, n0 = (bid / gx) * 128;

    const int wm = (wave >> 1) * 64, wn = (wave & 1) * 64;

    ffrag acc[4][4];
#pragma unroll
    for (int i = 0; i < 4; i++)
#pragma unroll
        for (int j = 0; j < 4; j++) acc[i][j] = ffrag{0.f, 0.f, 0.f, 0.f};

    const int ca = tid, cb = 256 + tid;
    const int ar0 = m0 + (ca >> 2), ar1 = m0 + (cb >> 2);
    const int k8a = (ca & 3) * 8, k8b = (cb & 3) * 8;
    const int wr0 = min(n0 + (ca >> 2), N - 1);   // clamp W rows (N tail)
    const int wr1 = min(n0 + (cb >> 2), N - 1);

    unsigned short* ldsA0 = As + (wave * 64) * 8;          // wave-uniform bases
    unsigned short* ldsA1 = As + (256 + wave * 64) * 8;
    unsigned short* ldsB0 = Bs + (wave * 64) * 8;
    unsigned short* ldsB1 = Bs + (256 + wave * 64) * 8;

    for (int k0 = 0; k0 < K; k0 += 32) {
        GLDS(A + (size_t)ar0 * K + k0 + k8a, ldsA0);
        GLDS(A + (size_t)ar1 * K + k0 + k8b, ldsA1);
        GLDS(W + (size_t)wr0 * K + k0 + k8a, ldsB0);
        GLDS(W + (size_t)wr1 * K + k0 + k8b, ldsB1);
        __syncthreads();
        bfrag af[4], bw[4];
#pragma unroll
        for (int i = 0; i < 4; i++)
            af[i] = *(const bfrag*)(As + (wm + i * 16 + lrow) * 32 + kq * 8);
#pragma unroll
        for (int j = 0; j < 4; j++)
            bw[j] = *(const bfrag*)(Bs + (wn + j * 16 + lrow) * 32 + kq * 8);
#pragma unroll
        for (int i = 0; i < 4; i++)
#pragma unroll
            for (int j = 0; j < 4; j++)
                acc[i][j] = __builtin_amdgcn_mfma_f32_16x16x32_bf16(af[i], bw[j], acc[i][j], 0, 0, 0);
        __syncthreads();
    }

    // epilogue: C/D layout col=lane&15, row=(lane>>4)*4+reg  [m89-verified]
#pragma unroll
    for (int j = 0; j < 4; j++) {
        int col  = n0 + wn + j * 16 + lrow;
        int colc = min(col, N - 1);
        float bs = 0.f;
        if (bias1) bs += bias1[colc];
        if (bias2) bs += bias2[colc];
        bool ok = (col < N);
#pragma unroll
        for (int i = 0; i < 4; i++) {
            int rbase = m0 + wm + i * 16 + kq * 4;
#pragma unroll
            for (int r = 0; r < 4; r++) {
                float v = acc[i][j][r] + bs;
                if (ok) outp[(size_t)(rbase + r) * N + col] = v;
            }
        }
    }
}

// ---------------------------------------------------------------------------
// Skewed fused LSTM step: one launch computes layer1@t1 (blocks 0..127) AND
// layer2@t2 = t1-1 (blocks 128..255) concurrently — they are independent.
// Launch k writes H0[k+1] / Htop[k]; reads H0[k] / Htop[k-1]: disjoint slices.
// Halves launch count (64 -> 33) and fills the GPU (256 blocks vs 128).
// ---------------------------------------------------------------------------
__global__ __launch_bounds__(256)
void lstm_step(const unsigned short* __restrict__ Wbih,   // [L,2048,512] bf16
               const unsigned short* __restrict__ Wbhh,   // [L,2048,512] bf16
               const float* __restrict__ X0,              // [T*B,2048] fp32
               const float* __restrict__ b_ih,            // [L,4E] fp32
               const float* __restrict__ b_hh,            // [L,4E] fp32
               unsigned short* __restrict__ H0,           // [(T+1),B,E] bf16
               unsigned short* __restrict__ Htop,         // [(T+1),B,E] bf16
               float* __restrict__ c0, float* __restrict__ c1,
               int t1, int t2)
{
    const int layer = blockIdx.x >> 7;
    const int blk   = blockIdx.x & 127;
    const int tid  = threadIdx.x;
    const int wave = tid >> 6, lane = tid & 63;
    const int lrow = lane & 15, kq = lane >> 4;
    const int b0 = (blk & 3) * 16;
    const int e0 = (blk >> 2) * 16;
    const int wr = wave * 512 + e0 + lrow;   // W row (gate = wave)
    const size_t BE = (size_t)B_ * E_;

    const unsigned short *xin, *hprev, *Wih, *Whh;
    const float *pre, *bih, *bhh;
    unsigned short* hout; float* cst;

    if (layer == 0) {
        if (t1 < 0) return;
        xin = nullptr; Wih = nullptr;
        Whh = Wbhh;                                    // layer-0 W_hh
        pre = X0 + (size_t)t1 * B_ * 2048;             // x@Wih + biases (precomputed)
        bih = nullptr; bhh = nullptr;
        hprev = H0 + (size_t)t1 * BE;
        hout  = H0 + (size_t)(t1 + 1) * BE;
        cst = c0;
    } else {
        if (t2 < 0) return;
        xin = H0 + (size_t)(t2 + 1) * BE;              // layer1 output @ t2
        Wih = Wbih + 2048 * 512;                       // layer-1 weights
        Whh = Wbhh + 2048 * 512;
        pre = nullptr;
        bih = b_ih + 2048; bhh = b_hh + 2048;
        hprev = Htop + (size_t)t2 * BE;
        hout  = Htop + (size_t)(t2 + 1) * BE;
        cst = c1;
    }

    ffrag acc = {0.f, 0.f, 0.f, 0.f};
    if (xin) {
#pragma unroll
        for (int k0 = 0; k0 < 512; k0 += 32) {
            bfrag a = *(const bfrag*)(xin + (b0 + lrow) * 512 + k0 + kq * 8);
            bfrag w = *(const bfrag*)(Wih + (size_t)wr * 512 + k0 + kq * 8);
            acc = __builtin_amdgcn_mfma_f32_16x16x32_bf16(a, w, acc, 0, 0, 0);
        }
    }
#pragma unroll
    for (int k0 = 0; k0 < 512; k0 += 32) {
        bfrag a = *(const bfrag*)(hprev + (b0 + lrow) * 512 + k0 + kq * 8);
        bfrag w = *(const bfrag*)(Whh + (size_t)wr * 512 + k0 + kq * 8);
        acc = __builtin_amdgcn_mfma_f32_16x16x32_bf16(a, w, acc, 0, 0, 0);
    }

    __shared__ float gb[4][16][17];   // [gate][b][e], +1 pad
#pragma unroll
    for (int r = 0; r < 4; r++) gb[wave][kq * 4 + r][lrow] = acc[r];
    __syncthreads();

    const int m = tid >> 4, el = tid & 15;
    const int b = b0 + m, e = e0 + el;
    float gi = gb[0][m][el], gf = gb[1][m][el], gg = gb[2][m][el], go = gb[3][m][el];
    if (pre) {
        const float* p = pre + (size_t)b * 2048;
        gi += p[e]; gf += p[512 + e]; gg += p[1024 + e]; go += p[1536 + e];
    }
    if (bih) {
        gi += bih[e]        + bhh[e];
        gf += bih[512 + e]  + bhh[512 + e];
        gg += bih[1024 + e] + bhh[1024 + e];
        go += bih[1536 + e] + bhh[1536 + e];
    }
    float cold = cst[(size_t)b * 512 + e];
    float cn = sigm(gf) * cold + sigm(gi) * tanhf(gg);
    float hn = sigm(go) * tanhf(cn);
    cst[(size_t)b * 512 + e]  = cn;
    hout[(size_t)b * 512 + e] = f2bf(hn);
}

// ---------------------------------------------------------------------------
// Attention over all (b,t) at once. block = one (b,t).
// Z[b*T+t] = [h_top(bf16 copy) | context(bf16)]. features fp32.
// ---------------------------------------------------------------------------
__global__ __launch_bounds__(256)
void attn_kernel(const float* __restrict__ features,          // [B,R,E] fp32
                 const unsigned short* __restrict__ Htop,     // [(T+1),B,E] bf16
                 unsigned short* __restrict__ Z)               // [B*T, 2E] bf16
{
    const int bt = blockIdx.x;            // = b*T + t
    const int b = bt >> 5, t = bt & 31;
    const unsigned short* h = Htop + ((size_t)(t + 1) * B_ + b) * E_;
    const float* f = features + (size_t)b * R_ * E_;
    const int tid = threadIdx.x, wave = tid >> 6, lane = tid & 63;

    __shared__ float hf[E_];
    __shared__ float sc[64];
    hf[tid]       = bf2f((short)h[tid]);
    hf[256 + tid] = bf2f((short)h[256 + tid]);
    __syncthreads();

    for (int r = wave; r < R_; r += 4) {
        const float4* fr = (const float4*)(f + r * E_ + lane * 8);
        float4 v0 = fr[0], v1 = fr[1];
        const float* hp = hf + lane * 8;
        float s = v0.x * hp[0] + v0.y * hp[1] + v0.z * hp[2] + v0.w * hp[3]
                + v1.x * hp[4] + v1.y * hp[5] + v1.z * hp[6] + v1.w * hp[7];
        for (int off = 32; off; off >>= 1) s += __shfl_down(s, off);
        if (lane == 0) sc[r] = s;
    }
    __syncthreads();
    if (tid < 64) {
        float v = (tid < R_) ? sc[tid] : -3.4e38f;
        float mx = v;
        for (int off = 32; off; off >>= 1) mx = fmaxf(mx, __shfl_xor(mx, off));
        float ex = (tid < R_) ? __expf(v - mx) : 0.f;
        float sum = ex;
        for (int off = 32; off; off >>= 1) sum += __shfl_xor(sum, off);
        if (tid < R_) sc[tid] = ex / sum;
    }
    __syncthreads();

    const int e0 = tid * 2;
    float c0 = 0.f, c1 = 0.f;
    for (int r = 0; r < R_; r++) {
        float a = sc[r];
        c0 += a * f[r * E_ + e0];
        c1 += a * f[r * E_ + e0 + 1];
    }
    unsigned short* zr = Z + (size_t)bt * (2 * E_);
    zr[e0] = h[e0]; zr[e0 + 1] = h[e0 + 1];          // bf16 copy of h_top
    zr[E_ + e0]     = f2bf(c0);
    zr[E_ + e0 + 1] = f2bf(c1);
}

// ---------------------------------------------------------------------------
// Init: mean_f -> c0/c1 (fp32) + h0 (bf16, both layers); gather+convert
// embeddings into Aemb [T*B, E] bf16.
// ---------------------------------------------------------------------------
__global__ __launch_bounds__(256)
void init_kernel(const float* __restrict__ features,
                 const int* __restrict__ captions,
                 const float* __restrict__ embed,
                 float* __restrict__ c0, float* __restrict__ c1,
                 unsigned short* __restrict__ H0, unsigned short* __restrict__ Htop,
                 unsigned short* __restrict__ Aemb)
{
    const int blk = blockIdx.x, tid = threadIdx.x;
    if (blk < 128) {
        int g = blk * 256 + tid;          // 0..B*E-1
        int b = g >> 9, e = g & 511;
        float s = 0.f;
        for (int r = 0; r < R_; r++) s += features[((size_t)b * R_ + r) * E_ + e];
        float mean = s * (1.f / 49.f);
        c0[g] = mean; c1[g] = mean;
        unsigned short mb = f2bf(mean);
        H0[g] = mb; Htop[g] = mb;
    } else {
        int idx = (blk - 128) * 256 + tid;        // chunk of 8 elems
        int row = idx >> 6, k8 = (idx & 63) * 8;  // row = t*B+b
        int bb = row & 63, tt = row >> 6;
        int tok = captions[bb * T_ + tt];
        const float4* s = (const float4*)(embed + (size_t)tok * E_ + k8);
        float4 a = s[0], bq = s[1];
        bfrag o;
        o[0] = (short)f2bf(a.x);  o[1] = (short)f2bf(a.y);
        o[2] = (short)f2bf(a.z);  o[3] = (short)f2bf(a.w);
        o[4] = (short)f2bf(bq.x); o[5] = (short)f2bf(bq.y);
        o[6] = (short)f2bf(bq.z); o[7] = (short)f2bf(bq.w);
        *(bfrag*)(Aemb + (size_t)row * E_ + k8) = o;
    }
}

// ---------------------------------------------------------------------------
extern "C" void kernel_launch(void* const* d_in, const int* in_sizes, int n_in,
                              void* d_out, int out_size, void* d_ws, size_t ws_size,
                              hipStream_t stream)
{
    const float* features = (const float*)d_in[0];
    const int*   captions = (const int*)d_in[1];
    const float* embed    = (const float*)d_in[2];
    const float* W_ih     = (const float*)d_in[3];
    const float* W_hh     = (const float*)d_in[4];
    const float* b_ih     = (const float*)d_in[5];
    const float* b_hh     = (const float*)d_in[6];
    const float* W_lin    = (const float*)d_in[7];
    const float* b_lin    = (const float*)d_in[8];
    float* out = (float*)d_out;

    char* ws = (char*)d_ws;
    float*          X0     = (float*)(ws);                       // [T*B,4E] fp32  16 MB
    unsigned short* H0     = (unsigned short*)(ws + 16777216);   // [(T+1),B,E] bf16
    unsigned short* Htop   = (unsigned short*)(ws + 18939904);   // [(T+1),B,E] bf16
    float*          c0     = (float*)(ws + 21102592);            // [B,E] fp32
    float*          c1     = (float*)(ws + 21233664);            // [B,E] fp32
    unsigned short* Z      = (unsigned short*)(ws + 21364736);   // [B*T,2E] bf16
    unsigned short* Aemb   = (unsigned short*)(ws + 25559040);   // [T*B,E] bf16
    unsigned short* Wb_ih  = (unsigned short*)(ws + 27656192);   // [L,4E,E] bf16
    unsigned short* Wb_hh  = (unsigned short*)(ws + 31850496);   // [L,4E,E] bf16
    unsigned short* Wb_lin = (unsigned short*)(ws + 36044800);   // [V,2E] bf16 61.4 MB

    // fp32 -> bf16 weight conversions
    cvt_kernel<<<1024, 256, 0, stream>>>(W_ih, Wb_ih, 2 * 2048 * 512 / 8);
    cvt_kernel<<<1024, 256, 0, stream>>>(W_hh, Wb_hh, 2 * 2048 * 512 / 8);
    cvt_kernel<<<15000, 256, 0, stream>>>(W_lin, Wb_lin, V_ * 1024 / 8);

    init_kernel<<<640, 256, 0, stream>>>(features, captions, embed, c0, c1, H0, Htop, Aemb);

    // X0 = Aemb @ W_ih[0]^T + b_ih[0] + b_hh[0]   (fp32, [T*B,4E])
    gemm_bt<<<dim3(16, 16), 256, 0, stream>>>(Aemb, Wb_ih, b_ih, b_hh, X0, 2048, 2048, 512);

    // Skewed fused recurrence: launch k = { layer1@k , layer2@(k-1) }, k=0..T
    for (int k = 0; k <= T_; k++) {
        lstm_step<<<256, 256, 0, stream>>>(Wb_ih, Wb_hh, X0, b_ih, b_hh,
                                           H0, Htop, c0, c1,
                                           (k < T_) ? k : -1, k - 1);
    }

    attn_kernel<<<B_ * T_, 256, 0, stream>>>(features, Htop, Z);

    // logits = Z @ W_lin^T + b_lin  -> fp32 out [B*T, V]
    gemm_bt<<<dim3(16, 235), 256, 0, stream>>>(Z, Wb_lin, b_lin, nullptr, out, 2048, V_, 1024);

    (void)in_sizes; (void)n_in; (void)out_size; (void)ws_size;
}